// Round 22
// baseline (1377.033 us; speedup 1.0000x reference)
//
#include <hip/hip_runtime.h>
#include <hip/hip_bf16.h>
#include <stdint.h>

#define N_TOK 8192
#define DIM   2048
#define FDIM  4096
#define NEXP  8

// ---- ws layout (bytes) ---- total EXACTLY 310,902,912 = round-1 proven floor
#define XB_OFF   0ull                        // bf16 x  [8192][2048]    33,554,432
#define HB_OFF   33554432ull                 // bf16 h  [18432][4096]  142,606,336 (17408 used)
#define WB1_OFF  176160768ull                // bf16 w1 half; later w2 FULL (134MB spans wb1+wb3)
#define WB3_OFF  243269632ull                // bf16 w3 half            67,108,864
#define META_OFF 310378496ull
#define CNT_OFF   (META_OFF)                 // int[8]
#define EBASE_OFF (META_OFF + 64ull)         // int[8]
#define ELIST_OFF (META_OFF + 128ull)        // int[8][8192]
#define EWTS_OFF  (ELIST_OFF + 262144ull)    // f32[8][8192] -> end 310,902,912

typedef float f32x4 __attribute__((ext_vector_type(4)));
typedef short s16x8 __attribute__((ext_vector_type(8)));

__device__ __forceinline__ uint32_t pkbf(float a, float b) {
  uint32_t ua = __builtin_bit_cast(uint32_t, a) + 0x8000u;
  uint32_t ub = __builtin_bit_cast(uint32_t, b) + 0x8000u;
  return (ua >> 16) | (ub & 0xffff0000u);
}

__device__ __forceinline__ void gld16(const void* g, void* l) {
  __builtin_amdgcn_global_load_lds(
      (__attribute__((address_space(1))) void*)g,
      (__attribute__((address_space(3))) void*)l, 16, 0, 0);
}

// convert 8-elem chunks of rows [r0,r0+nrh) of each expert's [rtot][kd] fp32
// matrix -> bf16 [e][nrh][kd]
__device__ __forceinline__ void conv_chunks(
    const float* __restrict__ src, __hip_bfloat16* __restrict__ dst,
    int r0, int nrh, int rtot, int kd, int idx0, int stride, int total) {
  const int cpr = kd / 8;
  for (int i = idx0; i < total; i += stride) {
    const int e = i / (nrh * cpr);
    const int rem = i - e * nrh * cpr;
    const int lr = rem / cpr;
    const int c = rem - lr * cpr;
    const float* s = src + ((size_t)e * rtot + r0 + lr) * (size_t)kd + c * 8;
    const float4 a = *(const float4*)s;
    const float4 b = *(const float4*)(s + 4);
    uint4 u;
    u.x = pkbf(a.x, a.y); u.y = pkbf(a.z, a.w);
    u.z = pkbf(b.x, b.y); u.w = pkbf(b.z, b.w);
    *(uint4*)(dst + ((size_t)e * nrh + lr) * (size_t)kd + c * 8) = u;
  }
}

__global__ void init_k(int* cnt) {
  if (threadIdx.x < NEXP) cnt[threadIdx.x] = 0;
}

// FAT router: blocks < N_TOK route one token (+x->bf16); then 4096 blocks
// convert w1 rows[0:2048) -> wb1, 4096 convert w3 rows[0:2048) -> wb3,
// 512 zero the output.
__global__ void router_k(const float* __restrict__ x, const float* __restrict__ gw,
                         __hip_bfloat16* __restrict__ xb, int* __restrict__ cnt,
                         int* __restrict__ elist, float* __restrict__ ewts,
                         const float* __restrict__ w1, const float* __restrict__ w3,
                         __hip_bfloat16* __restrict__ wA, __hip_bfloat16* __restrict__ wB,
                         float* __restrict__ out) {
  const int blk = blockIdx.x;
  const int t = threadIdx.x;
  if (blk >= N_TOK) {
    const int cb = blk - N_TOK;                      // 0..8703
    if (cb < 4096) {
      conv_chunks(w1, wA, 0, 2048, FDIM, DIM, cb * 256 + t, 4096 * 256, 4194304);
    } else if (cb < 8192) {
      conv_chunks(w3, wB, 0, 2048, FDIM, DIM, (cb - 4096) * 256 + t, 4096 * 256, 4194304);
    } else {
      for (size_t i = (size_t)(cb - 8192) * 256 + t; i < 4194304; i += 512 * 256)
        *(float4*)(out + i * 4) = make_float4(0.f, 0.f, 0.f, 0.f);
    }
    return;
  }
  const int n = blk;
  const float* xr = x + (size_t)n * DIM;
  const float4 v0 = *(const float4*)(xr + t * 8);
  const float4 v1 = *(const float4*)(xr + t * 8 + 4);
  uint4 u;
  u.x = pkbf(v0.x, v0.y); u.y = pkbf(v0.z, v0.w);
  u.z = pkbf(v1.x, v1.y); u.w = pkbf(v1.z, v1.w);
  *(uint4*)(xb + (size_t)n * DIM + t * 8) = u;

  float p[NEXP];
#pragma unroll
  for (int e = 0; e < NEXP; ++e) {
    const float* g = gw + e * DIM + t * 8;
    const float4 g0 = *(const float4*)g;
    const float4 g1 = *(const float4*)(g + 4);
    p[e] = v0.x * g0.x + v0.y * g0.y + v0.z * g0.z + v0.w * g0.w +
           v1.x * g1.x + v1.y * g1.y + v1.z * g1.z + v1.w * g1.w;
  }
#pragma unroll
  for (int off = 32; off >= 1; off >>= 1)
#pragma unroll
    for (int e = 0; e < NEXP; ++e) p[e] += __shfl_xor(p[e], off, 64);

  __shared__ float red[4][NEXP];
  const int lane = t & 63, wv = t >> 6;
  if (lane == 0) {
#pragma unroll
    for (int e = 0; e < NEXP; ++e) red[wv][e] = p[e];
  }
  __syncthreads();
  if (t == 0) {
    float l0 = -1e30f, l1 = -1e30f;
    int e0 = 0, e1 = 0;
#pragma unroll
    for (int e = 0; e < NEXP; ++e) {
      float v = red[0][e] + red[1][e] + red[2][e] + red[3][e];
      if (v > l0) { l1 = l0; e1 = e0; l0 = v; e0 = e; }
      else if (v > l1) { l1 = v; e1 = e; }
    }
    const float ed = expf(l1 - l0);
    const float inv = 1.f / (1.f + ed);
    int s0 = atomicAdd(cnt + e0, 1);
    elist[e0 * N_TOK + s0] = n;
    ewts[e0 * N_TOK + s0] = inv;
    int s1 = atomicAdd(cnt + e1, 1);
    elist[e1 * N_TOK + s1] = (int)((uint32_t)n | 0x80000000u);
    ewts[e1 * N_TOK + s1] = ed * inv;
  }
}

__global__ void scan_k(const int* __restrict__ cnt, int* __restrict__ ebase) {
  if (threadIdx.x == 0 && blockIdx.x == 0) {
    int b = 0;
    for (int e = 0; e < NEXP; ++e) { ebase[e] = b; b += (cnt[e] + 127) & ~127; }
  }
}

// w1/w3 half-1 conversion in ONE launch: rows [r0,r0+2048)
__global__ void convH_k(const float* __restrict__ w1, __hip_bfloat16* __restrict__ d1,
                        const float* __restrict__ w3, __hip_bfloat16* __restrict__ d3,
                        int r0) {
  const int idx0 = blockIdx.x * 256 + threadIdx.x;   // 4096 blocks
  conv_chunks(w1, d1, r0, 2048, FDIM, DIM, idx0, 4096 * 256, 4194304);
  conv_chunks(w3, d3, r0, 2048, FDIM, DIM, idx0, 4096 * 256, 4194304);
}

// generic row-range conversion (used for full w2)
__global__ void convW_k(const float* __restrict__ src, __hip_bfloat16* __restrict__ dst,
                        int r0, int nrh, int rtot, int kd) {
  conv_chunks(src, dst, r0, nrh, rtot, kd,
              blockIdx.x * blockDim.x + threadIdx.x, gridDim.x * blockDim.x,
              NEXP * nrh * (kd / 8));
}

// ============================================================================
// Fused gate+up grouped GEMM — ROUND-21 EXACT (3-stage + counted vmcnt(6),
// 128x128 tile, 2 blocks/CU, setprio around MFMA cluster).
// ============================================================================
__global__ __launch_bounds__(256, 2) void moe_up_k(
    const __hip_bfloat16* __restrict__ xb, const __hip_bfloat16* __restrict__ w1b,
    const __hip_bfloat16* __restrict__ w3b, __hip_bfloat16* __restrict__ hb,
    const int* __restrict__ cnt, const int* __restrict__ ebase,
    const int* __restrict__ elist, int noff) {
  constexpr int NT = DIM / 32;               // 64 K-steps
  const int e = blockIdx.z;
  const int count = cnt[e];
  const int mt = blockIdx.y;
  if (mt * 128 >= count) return;
  const int bn0 = blockIdx.x * 128;          // col base within half
  const int ncol0 = noff + bn0;              // global F col base

  __shared__ char lds[73728];                // 3 bufs x (A 8K | B1 8K | B3 8K)
  const int t = threadIdx.x;
  const int lane = t & 63, wv = t >> 6;
  const int wr = wv >> 1, wc = wv & 1;
  const int* lst = elist + e * N_TOK;
  const size_t hrow0 = (size_t)ebase[e] + (size_t)mt * 128;

  const int r0 = t >> 2;
  const int ks = (t & 3) ^ ((r0 >> 1) & 3);   // pre-swizzled source granule
  size_t sA[2], sB1[2];
  int ldsO[2];
#pragma unroll
  for (int i = 0; i < 2; ++i) {
    const int r = r0 + i * 64;
    int idx = mt * 128 + r;
    if (idx >= count) idx = 0;                 // clamp pad rows
    const size_t tok = (size_t)(lst[idx] & 0x7fffffff);
    sA[i] = tok * DIM + ks * 8;
    sB1[i] = ((size_t)e * 2048 + bn0 + r) * DIM + ks * 8;
    ldsO[i] = i * 4096 + wv * 1024;            // + lane*16 applied by HW
  }

  const int fr = lane & 15;
  const int swzc = ((lane >> 4) ^ ((fr >> 1) & 3)) << 4;
  const int aoff = (wr * 64 + fr) * 64 + swzc;
  const int boff = (wc * 64 + fr) * 64 + swzc;

  f32x4 accG[4][4], accU[4][4];
#pragma unroll
  for (int mi = 0; mi < 4; ++mi)
#pragma unroll
    for (int ni = 0; ni < 4; ++ni) {
      accG[mi][ni] = {0.f, 0.f, 0.f, 0.f};
      accU[mi][ni] = {0.f, 0.f, 0.f, 0.f};
    }

  auto stage = [&](int kt, int b) {            // 6 gld16, always
    const int k0 = kt * 32;
    char* base = lds + b * 24576;
#pragma unroll
    for (int i = 0; i < 2; ++i)
      gld16(xb + sA[i] + k0, base + ldsO[i]);
#pragma unroll
    for (int i = 0; i < 2; ++i)
      gld16(w1b + sB1[i] + k0, base + 8192 + ldsO[i]);
#pragma unroll
    for (int i = 0; i < 2; ++i)
      gld16(w3b + sB1[i] + k0, base + 16384 + ldsO[i]);
  };

  stage(0, 0);
  stage(1, 1);
  asm volatile("s_waitcnt vmcnt(6)" ::: "memory");
  __builtin_amdgcn_sched_barrier(0);
  __builtin_amdgcn_s_barrier();
  __builtin_amdgcn_sched_barrier(0);

  int bR = 0, bS = 2;                          // read buf, stage buf
#pragma unroll 3
  for (int kt = 0; kt < NT; ++kt) {
    const int t2 = (kt + 2 < NT) ? kt + 2 : NT - 1;   // clamp: uniform counts
    stage(t2, bS);
    char* base = lds + bR * 24576;
    s16x8 af[4], b1f[4], b3f[4];
#pragma unroll
    for (int mi = 0; mi < 4; ++mi)
      af[mi] = *(const s16x8*)(base + aoff + mi * 1024);
#pragma unroll
    for (int ni = 0; ni < 4; ++ni) {
      b1f[ni] = *(const s16x8*)(base + 8192 + boff + ni * 1024);
      b3f[ni] = *(const s16x8*)(base + 16384 + boff + ni * 1024);
    }
    __builtin_amdgcn_s_setprio(1);
#pragma unroll
    for (int mi = 0; mi < 4; ++mi)
#pragma unroll
      for (int ni = 0; ni < 4; ++ni) {
        accG[mi][ni] = __builtin_amdgcn_mfma_f32_16x16x32_bf16(
            af[mi], b1f[ni], accG[mi][ni], 0, 0, 0);
        accU[mi][ni] = __builtin_amdgcn_mfma_f32_16x16x32_bf16(
            af[mi], b3f[ni], accU[mi][ni], 0, 0, 0);
      }
    __builtin_amdgcn_s_setprio(0);
    asm volatile("s_waitcnt vmcnt(6)" ::: "memory");   // tile kt+1 published
    __builtin_amdgcn_sched_barrier(0);
    __builtin_amdgcn_s_barrier();
    __builtin_amdgcn_sched_barrier(0);
    bR = (bR == 2) ? 0 : bR + 1;
    bS = (bS == 2) ? 0 : bS + 1;
  }

  const int erow = (lane >> 4) * 4;
  const int ecol = lane & 15;
#pragma unroll
  for (int mi = 0; mi < 4; ++mi)
#pragma unroll
    for (int ni = 0; ni < 4; ++ni) {
      const size_t cb = ncol0 + wc * 64 + ni * 16 + ecol;
#pragma unroll
      for (int j = 0; j < 4; ++j) {
        const size_t r = hrow0 + wr * 64 + mi * 16 + erow + j;
        const float g = accG[mi][ni][j];
        const float uu = accU[mi][ni][j];
        const float h = g / (1.f + __expf(-g)) * uu;
        hb[r * FDIM + cb] = __float2bfloat16(h);
      }
    }
}

// ============================================================================
// Down grouped GEMM — 128x128 tile @ 3 blocks/CU (24 waves/CU): LDS 48KB
// (3 bufs x (A 8K | B 8K)), 3-stage rotation + counted vmcnt(4), setprio.
// Occupancy is the session's proven dominant variable; staged-byte volume is
// proven irrelevant (r15/r18/r19/r20). launch_bounds(256,3): VGPR cap 170 >>
// ~95 needed (acc 64) -> no spill. Grid panel-fastest. atomicAdd epilogue.
// ============================================================================
__global__ __launch_bounds__(256, 3) void moe_down_k(
    const __hip_bfloat16* __restrict__ hb, const __hip_bfloat16* __restrict__ w2b,
    float* __restrict__ out, const int* __restrict__ cnt,
    const int* __restrict__ ebase, const int* __restrict__ elist,
    const float* __restrict__ ewts) {
  constexpr int NT = FDIM / 32;              // 128 K-steps
  const int e = blockIdx.z;
  const int count = cnt[e];
  const int mt = blockIdx.y;
  if (mt * 128 >= count) return;
  const int bn0 = blockIdx.x * 128;          // D col base (one 128-panel)

  __shared__ char lds[49152];                // 3 bufs x (A 8K | B 8K)
  const int t = threadIdx.x;
  const int lane = t & 63, wv = t >> 6;
  const int wr = wv >> 1, wc = wv & 1;
  const int* lst = elist + e * N_TOK;
  const size_t hrow0 = (size_t)ebase[e] + (size_t)mt * 128;

  const int r0 = t >> 2;
  const int ks = (t & 3) ^ ((r0 >> 1) & 3);
  size_t sA[2], sB[2];
  int ldsO[2];
#pragma unroll
  for (int i = 0; i < 2; ++i) {
    const int r = r0 + i * 64;
    sA[i] = (hrow0 + r) * (size_t)FDIM + ks * 8;
    sB[i] = ((size_t)e * 2048 + bn0 + r) * (size_t)FDIM + ks * 8;
    ldsO[i] = i * 4096 + wv * 1024;
  }

  const int fr = lane & 15;
  const int swzc = ((lane >> 4) ^ ((fr >> 1) & 3)) << 4;
  const int aoff = (wr * 64 + fr) * 64 + swzc;
  const int boff = 8192 + (wc * 64 + fr) * 64 + swzc;

  f32x4 acc[4][4];
#pragma unroll
  for (int mi = 0; mi < 4; ++mi)
#pragma unroll
    for (int ni = 0; ni < 4; ++ni) acc[mi][ni] = {0.f, 0.f, 0.f, 0.f};

  auto stage = [&](int kt, int b) {          // 4 gld16, always
    const int k0 = kt * 32;
    char* base = lds + b * 16384;
#pragma unroll
    for (int i = 0; i < 2; ++i)
      gld16(hb + sA[i] + k0, base + ldsO[i]);
#pragma unroll
    for (int i = 0; i < 2; ++i)
      gld16(w2b + sB[i] + k0, base + 8192 + ldsO[i]);
  };

  stage(0, 0);
  stage(1, 1);
  asm volatile("s_waitcnt vmcnt(4)" ::: "memory");
  __builtin_amdgcn_sched_barrier(0);
  __builtin_amdgcn_s_barrier();
  __builtin_amdgcn_sched_barrier(0);

  int bR = 0, bS = 2;                        // read buf, stage buf
#pragma unroll 3
  for (int kt = 0; kt < NT; ++kt) {
    const int t2 = (kt + 2 < NT) ? kt + 2 : NT - 1;   // clamp: uniform counts
    stage(t2, bS);
    char* base = lds + bR * 16384;
    s16x8 af[4], bf[4];
#pragma unroll
    for (int mi = 0; mi < 4; ++mi)
      af[mi] = *(const s16x8*)(base + aoff + mi * 1024);
#pragma unroll
    for (int ni = 0; ni < 4; ++ni)
      bf[ni] = *(const s16x8*)(base + boff + ni * 1024);
    __builtin_amdgcn_s_setprio(1);
#pragma unroll
    for (int mi = 0; mi < 4; ++mi)
#pragma unroll
      for (int ni = 0; ni < 4; ++ni)
        acc[mi][ni] = __builtin_amdgcn_mfma_f32_16x16x32_bf16(
            af[mi], bf[ni], acc[mi][ni], 0, 0, 0);
    __builtin_amdgcn_s_setprio(0);
    asm volatile("s_waitcnt vmcnt(4)" ::: "memory");   // tile kt+1 published
    __builtin_amdgcn_sched_barrier(0);
    __builtin_amdgcn_s_barrier();
    __builtin_amdgcn_sched_barrier(0);
    bR = (bR == 2) ? 0 : bR + 1;
    bS = (bS == 2) ? 0 : bS + 1;
  }

  const int erow = (lane >> 4) * 4;
  const int ecol = lane & 15;
#pragma unroll
  for (int mi = 0; mi < 4; ++mi)
#pragma unroll
    for (int j = 0; j < 4; ++j) {
      const int i = mt * 128 + wr * 64 + mi * 16 + erow + j;
      if (i < count) {
        const uint32_t info = (uint32_t)lst[i];
        const int tok = (int)(info & 0x7fffffffu);
        const float wt = ewts[e * N_TOK + i];
        float* prow = out + (size_t)tok * DIM;
#pragma unroll
        for (int ni = 0; ni < 4; ++ni) {
          const int cb = bn0 + wc * 64 + ni * 16 + ecol;
          atomicAdd(prow + cb, wt * acc[mi][ni][j]);
        }
      }
    }
}

extern "C" void kernel_launch(void* const* d_in, const int* in_sizes, int n_in,
                              void* d_out, int out_size, void* d_ws, size_t ws_size,
                              hipStream_t stream) {
  const float* stm = (const float*)d_in[0];
  const float* gw = (const float*)d_in[1];
  const float* w1 = (const float*)d_in[2];
  const float* w2 = (const float*)d_in[3];
  const float* w3 = (const float*)d_in[4];
  float* out = (float*)d_out;
  char* ws = (char*)d_ws;

  __hip_bfloat16* xb = (__hip_bfloat16*)(ws + XB_OFF);
  __hip_bfloat16* hb = (__hip_bfloat16*)(ws + HB_OFF);
  __hip_bfloat16* wb1 = (__hip_bfloat16*)(ws + WB1_OFF);
  __hip_bfloat16* wb3 = (__hip_bfloat16*)(ws + WB3_OFF);
  __hip_bfloat16* w2full = (__hip_bfloat16*)(ws + WB1_OFF);  // 134MB spans wb1+wb3
  int* cnt = (int*)(ws + CNT_OFF);
  int* ebase = (int*)(ws + EBASE_OFF);
  int* elist = (int*)(ws + ELIST_OFF);
  float* ewts = (float*)(ws + EWTS_OFF);

  init_k<<<1, 64, 0, stream>>>(cnt);
  // FAT router: 8192 route + 4096 conv-w1h0->wb1 + 4096 conv-w3h0->wb3 + 512 zero
  router_k<<<N_TOK + 8704, 256, 0, stream>>>(stm, gw, xb, cnt, elist, ewts,
                                             w1, w3, wb1, wb3, out);
  scan_k<<<1, 64, 0, stream>>>(cnt, ebase);

  const dim3 gUp(16, 64, 8);   // (N-panels/half, M-tiles, experts)
  const dim3 gDn(16, 64, 8);   // (128-col D panels fastest, M-tiles, experts)

  // up F-half 0 (weights converted by fat router)
  moe_up_k<<<gUp, 256, 0, stream>>>(xb, wb1, wb3, hb, cnt, ebase, elist, 0);

  // convert w1h1 -> wb1 and w3h1 -> wb3 in ONE launch, then up F-half 1
  convH_k<<<4096, 256, 0, stream>>>(w1, wb1, w3, wb3, 2048);
  moe_up_k<<<gUp, 256, 0, stream>>>(xb, wb1, wb3, hb, cnt, ebase, elist, 2048);

  // full w2 -> bf16 (wb1+wb3 both dead), then one fused down launch
  convW_k<<<4096, 256, 0, stream>>>(w2, w2full, 0, 2048, DIM, FDIM);
  moe_down_k<<<gDn, 256, 0, stream>>>(hb, w2full, out, cnt, ebase, elist, ewts);
}

// Round 23
// 1331.468 us; speedup vs baseline: 1.0342x; 1.0342x over previous
//
#include <hip/hip_runtime.h>
#include <hip/hip_bf16.h>
#include <stdint.h>

#define N_TOK 8192
#define DIM   2048
#define FDIM  4096
#define NEXP  8

// ---- ws layout (bytes) ---- total EXACTLY 310,902,912 = round-1 proven floor
#define XB_OFF   0ull                        // bf16 x  [8192][2048]    33,554,432
#define HB_OFF   33554432ull                 // bf16 h  [18432][4096]  142,606,336 (17408 used)
#define WB1_OFF  176160768ull                // bf16 w1 half; later w2 FULL (134MB spans wb1+wb3)
#define WB3_OFF  243269632ull                // bf16 w3 half            67,108,864
#define META_OFF 310378496ull
#define CNT_OFF   (META_OFF)                 // int[8]
#define EBASE_OFF (META_OFF + 64ull)         // int[8]
#define ELIST_OFF (META_OFF + 128ull)        // int[8][8192]
#define EWTS_OFF  (ELIST_OFF + 262144ull)    // f32[8][8192] -> end 310,902,912

typedef float f32x4 __attribute__((ext_vector_type(4)));
typedef short s16x8 __attribute__((ext_vector_type(8)));

__device__ __forceinline__ uint32_t pkbf(float a, float b) {
  uint32_t ua = __builtin_bit_cast(uint32_t, a) + 0x8000u;
  uint32_t ub = __builtin_bit_cast(uint32_t, b) + 0x8000u;
  return (ua >> 16) | (ub & 0xffff0000u);
}

__device__ __forceinline__ void gld16(const void* g, void* l) {
  __builtin_amdgcn_global_load_lds(
      (__attribute__((address_space(1))) void*)g,
      (__attribute__((address_space(3))) void*)l, 16, 0, 0);
}

// convert 8-elem chunks of rows [r0,r0+nrh) of each expert's [rtot][kd] fp32
// matrix -> bf16 [e][nrh][kd]
__device__ __forceinline__ void conv_chunks(
    const float* __restrict__ src, __hip_bfloat16* __restrict__ dst,
    int r0, int nrh, int rtot, int kd, int idx0, int stride, int total) {
  const int cpr = kd / 8;
  for (int i = idx0; i < total; i += stride) {
    const int e = i / (nrh * cpr);
    const int rem = i - e * nrh * cpr;
    const int lr = rem / cpr;
    const int c = rem - lr * cpr;
    const float* s = src + ((size_t)e * rtot + r0 + lr) * (size_t)kd + c * 8;
    const float4 a = *(const float4*)s;
    const float4 b = *(const float4*)(s + 4);
    uint4 u;
    u.x = pkbf(a.x, a.y); u.y = pkbf(a.z, a.w);
    u.z = pkbf(b.x, b.y); u.w = pkbf(b.z, b.w);
    *(uint4*)(dst + ((size_t)e * nrh + lr) * (size_t)kd + c * 8) = u;
  }
}

__global__ void init_k(int* cnt) {
  if (threadIdx.x < NEXP) cnt[threadIdx.x] = 0;
}

// FAT router: blocks < N_TOK route one token (+x->bf16); then 4096 blocks
// convert w1 rows[0:2048) -> wb1, 4096 convert w3 rows[0:2048) -> wb3,
// 512 zero the output.
__global__ void router_k(const float* __restrict__ x, const float* __restrict__ gw,
                         __hip_bfloat16* __restrict__ xb, int* __restrict__ cnt,
                         int* __restrict__ elist, float* __restrict__ ewts,
                         const float* __restrict__ w1, const float* __restrict__ w3,
                         __hip_bfloat16* __restrict__ wA, __hip_bfloat16* __restrict__ wB,
                         float* __restrict__ out) {
  const int blk = blockIdx.x;
  const int t = threadIdx.x;
  if (blk >= N_TOK) {
    const int cb = blk - N_TOK;                      // 0..8703
    if (cb < 4096) {
      conv_chunks(w1, wA, 0, 2048, FDIM, DIM, cb * 256 + t, 4096 * 256, 4194304);
    } else if (cb < 8192) {
      conv_chunks(w3, wB, 0, 2048, FDIM, DIM, (cb - 4096) * 256 + t, 4096 * 256, 4194304);
    } else {
      for (size_t i = (size_t)(cb - 8192) * 256 + t; i < 4194304; i += 512 * 256)
        *(float4*)(out + i * 4) = make_float4(0.f, 0.f, 0.f, 0.f);
    }
    return;
  }
  const int n = blk;
  const float* xr = x + (size_t)n * DIM;
  const float4 v0 = *(const float4*)(xr + t * 8);
  const float4 v1 = *(const float4*)(xr + t * 8 + 4);
  uint4 u;
  u.x = pkbf(v0.x, v0.y); u.y = pkbf(v0.z, v0.w);
  u.z = pkbf(v1.x, v1.y); u.w = pkbf(v1.z, v1.w);
  *(uint4*)(xb + (size_t)n * DIM + t * 8) = u;

  float p[NEXP];
#pragma unroll
  for (int e = 0; e < NEXP; ++e) {
    const float* g = gw + e * DIM + t * 8;
    const float4 g0 = *(const float4*)g;
    const float4 g1 = *(const float4*)(g + 4);
    p[e] = v0.x * g0.x + v0.y * g0.y + v0.z * g0.z + v0.w * g0.w +
           v1.x * g1.x + v1.y * g1.y + v1.z * g1.z + v1.w * g1.w;
  }
#pragma unroll
  for (int off = 32; off >= 1; off >>= 1)
#pragma unroll
    for (int e = 0; e < NEXP; ++e) p[e] += __shfl_xor(p[e], off, 64);

  __shared__ float red[4][NEXP];
  const int lane = t & 63, wv = t >> 6;
  if (lane == 0) {
#pragma unroll
    for (int e = 0; e < NEXP; ++e) red[wv][e] = p[e];
  }
  __syncthreads();
  if (t == 0) {
    float l0 = -1e30f, l1 = -1e30f;
    int e0 = 0, e1 = 0;
#pragma unroll
    for (int e = 0; e < NEXP; ++e) {
      float v = red[0][e] + red[1][e] + red[2][e] + red[3][e];
      if (v > l0) { l1 = l0; e1 = e0; l0 = v; e0 = e; }
      else if (v > l1) { l1 = v; e1 = e; }
    }
    const float ed = expf(l1 - l0);
    const float inv = 1.f / (1.f + ed);
    int s0 = atomicAdd(cnt + e0, 1);
    elist[e0 * N_TOK + s0] = n;
    ewts[e0 * N_TOK + s0] = inv;
    int s1 = atomicAdd(cnt + e1, 1);
    elist[e1 * N_TOK + s1] = (int)((uint32_t)n | 0x80000000u);
    ewts[e1 * N_TOK + s1] = ed * inv;
  }
}

__global__ void scan_k(const int* __restrict__ cnt, int* __restrict__ ebase) {
  if (threadIdx.x == 0 && blockIdx.x == 0) {
    int b = 0;
    for (int e = 0; e < NEXP; ++e) { ebase[e] = b; b += (cnt[e] + 127) & ~127; }
  }
}

// w1/w3 half-1 conversion in ONE launch: rows [r0,r0+2048)
__global__ void convH_k(const float* __restrict__ w1, __hip_bfloat16* __restrict__ d1,
                        const float* __restrict__ w3, __hip_bfloat16* __restrict__ d3,
                        int r0) {
  const int idx0 = blockIdx.x * 256 + threadIdx.x;   // 4096 blocks
  conv_chunks(w1, d1, r0, 2048, FDIM, DIM, idx0, 4096 * 256, 4194304);
  conv_chunks(w3, d3, r0, 2048, FDIM, DIM, idx0, 4096 * 256, 4194304);
}

// generic row-range conversion (used for full w2)
__global__ void convW_k(const float* __restrict__ src, __hip_bfloat16* __restrict__ dst,
                        int r0, int nrh, int rtot, int kd) {
  conv_chunks(src, dst, r0, nrh, rtot, kd,
              blockIdx.x * blockDim.x + threadIdx.x, gridDim.x * blockDim.x,
              NEXP * nrh * (kd / 8));
}

// ============================================================================
// Fused gate+up grouped GEMM — r13/r19 structure (3-stage + counted vmcnt(6),
// 128x128 tile, 2 blocks/CU) + T5 setprio around the MFMA cluster
// (arbitrates between the 2 co-resident blocks' phase-offset waves).
// ============================================================================
__global__ __launch_bounds__(256, 2) void moe_up_k(
    const __hip_bfloat16* __restrict__ xb, const __hip_bfloat16* __restrict__ w1b,
    const __hip_bfloat16* __restrict__ w3b, __hip_bfloat16* __restrict__ hb,
    const int* __restrict__ cnt, const int* __restrict__ ebase,
    const int* __restrict__ elist, int noff) {
  constexpr int NT = DIM / 32;               // 64 K-steps
  const int e = blockIdx.z;
  const int count = cnt[e];
  const int mt = blockIdx.y;
  if (mt * 128 >= count) return;
  const int bn0 = blockIdx.x * 128;          // col base within half
  const int ncol0 = noff + bn0;              // global F col base

  __shared__ char lds[73728];                // 3 bufs x (A 8K | B1 8K | B3 8K)
  const int t = threadIdx.x;
  const int lane = t & 63, wv = t >> 6;
  const int wr = wv >> 1, wc = wv & 1;
  const int* lst = elist + e * N_TOK;
  const size_t hrow0 = (size_t)ebase[e] + (size_t)mt * 128;

  const int r0 = t >> 2;
  const int ks = (t & 3) ^ ((r0 >> 1) & 3);   // pre-swizzled source granule
  size_t sA[2], sB1[2];
  int ldsO[2];
#pragma unroll
  for (int i = 0; i < 2; ++i) {
    const int r = r0 + i * 64;
    int idx = mt * 128 + r;
    if (idx >= count) idx = 0;                 // clamp pad rows
    const size_t tok = (size_t)(lst[idx] & 0x7fffffff);
    sA[i] = tok * DIM + ks * 8;
    sB1[i] = ((size_t)e * 2048 + bn0 + r) * DIM + ks * 8;
    ldsO[i] = i * 4096 + wv * 1024;            // + lane*16 applied by HW
  }

  const int fr = lane & 15;
  const int swzc = ((lane >> 4) ^ ((fr >> 1) & 3)) << 4;
  const int aoff = (wr * 64 + fr) * 64 + swzc;
  const int boff = (wc * 64 + fr) * 64 + swzc;

  f32x4 accG[4][4], accU[4][4];
#pragma unroll
  for (int mi = 0; mi < 4; ++mi)
#pragma unroll
    for (int ni = 0; ni < 4; ++ni) {
      accG[mi][ni] = {0.f, 0.f, 0.f, 0.f};
      accU[mi][ni] = {0.f, 0.f, 0.f, 0.f};
    }

  auto stage = [&](int kt, int b) {            // 6 gld16, always
    const int k0 = kt * 32;
    char* base = lds + b * 24576;
#pragma unroll
    for (int i = 0; i < 2; ++i)
      gld16(xb + sA[i] + k0, base + ldsO[i]);
#pragma unroll
    for (int i = 0; i < 2; ++i)
      gld16(w1b + sB1[i] + k0, base + 8192 + ldsO[i]);
#pragma unroll
    for (int i = 0; i < 2; ++i)
      gld16(w3b + sB1[i] + k0, base + 16384 + ldsO[i]);
  };

  stage(0, 0);
  stage(1, 1);
  asm volatile("s_waitcnt vmcnt(6)" ::: "memory");
  __builtin_amdgcn_sched_barrier(0);
  __builtin_amdgcn_s_barrier();
  __builtin_amdgcn_sched_barrier(0);

  int bR = 0, bS = 2;                          // read buf, stage buf
#pragma unroll 3
  for (int kt = 0; kt < NT; ++kt) {
    const int t2 = (kt + 2 < NT) ? kt + 2 : NT - 1;   // clamp: uniform counts
    stage(t2, bS);
    char* base = lds + bR * 24576;
    s16x8 af[4], b1f[4], b3f[4];
#pragma unroll
    for (int mi = 0; mi < 4; ++mi)
      af[mi] = *(const s16x8*)(base + aoff + mi * 1024);
#pragma unroll
    for (int ni = 0; ni < 4; ++ni) {
      b1f[ni] = *(const s16x8*)(base + 8192 + boff + ni * 1024);
      b3f[ni] = *(const s16x8*)(base + 16384 + boff + ni * 1024);
    }
    __builtin_amdgcn_s_setprio(1);
#pragma unroll
    for (int mi = 0; mi < 4; ++mi)
#pragma unroll
      for (int ni = 0; ni < 4; ++ni) {
        accG[mi][ni] = __builtin_amdgcn_mfma_f32_16x16x32_bf16(
            af[mi], b1f[ni], accG[mi][ni], 0, 0, 0);
        accU[mi][ni] = __builtin_amdgcn_mfma_f32_16x16x32_bf16(
            af[mi], b3f[ni], accU[mi][ni], 0, 0, 0);
      }
    __builtin_amdgcn_s_setprio(0);
    asm volatile("s_waitcnt vmcnt(6)" ::: "memory");   // tile kt+1 published
    __builtin_amdgcn_sched_barrier(0);
    __builtin_amdgcn_s_barrier();
    __builtin_amdgcn_sched_barrier(0);
    bR = (bR == 2) ? 0 : bR + 1;
    bS = (bS == 2) ? 0 : bS + 1;
  }

  const int erow = (lane >> 4) * 4;
  const int ecol = lane & 15;
#pragma unroll
  for (int mi = 0; mi < 4; ++mi)
#pragma unroll
    for (int ni = 0; ni < 4; ++ni) {
      const size_t cb = ncol0 + wc * 64 + ni * 16 + ecol;
#pragma unroll
      for (int j = 0; j < 4; ++j) {
        const size_t r = hrow0 + wr * 64 + mi * 16 + erow + j;
        const float g = accG[mi][ni][j];
        const float uu = accU[mi][ni][j];
        const float h = g / (1.f + __expf(-g)) * uu;
        hb[r * FDIM + cb] = __float2bfloat16(h);
      }
    }
}

// ============================================================================
// Fused down grouped GEMM — r19 structure (panel-fastest grid, 3-stage +
// counted vmcnt(6), 128x256 tile via two B panels sharing staged h tile)
// + T5 setprio around the MFMA cluster.
// ============================================================================
__global__ __launch_bounds__(256, 2) void moe_down_k(
    const __hip_bfloat16* __restrict__ hb, const __hip_bfloat16* __restrict__ w2b,
    float* __restrict__ out, const int* __restrict__ cnt,
    const int* __restrict__ ebase, const int* __restrict__ elist,
    const float* __restrict__ ewts) {
  constexpr int NT = FDIM / 32;              // 128 K-steps
  const int e = blockIdx.z;
  const int count = cnt[e];
  const int mt = blockIdx.y;
  if (mt * 128 >= count) return;
  const int bn0 = blockIdx.x * 256;          // D col base (two 128-panels)

  __shared__ char lds[73728];                // 3 bufs x (A 8K | B0 8K | B1 8K)
  const int t = threadIdx.x;
  const int lane = t & 63, wv = t >> 6;
  const int wr = wv >> 1, wc = wv & 1;
  const int* lst = elist + e * N_TOK;
  const size_t hrow0 = (size_t)ebase[e] + (size_t)mt * 128;

  const int r0 = t >> 2;
  const int ks = (t & 3) ^ ((r0 >> 1) & 3);
  size_t sA[2], sB[2];
  int ldsO[2];
#pragma unroll
  for (int i = 0; i < 2; ++i) {
    const int r = r0 + i * 64;
    sA[i] = (hrow0 + r) * (size_t)FDIM + ks * 8;
    sB[i] = ((size_t)e * 2048 + bn0 + r) * (size_t)FDIM + ks * 8;  // panel0 rows
    ldsO[i] = i * 4096 + wv * 1024;
  }
  const size_t sBp = 128 * (size_t)FDIM;     // +128 rows -> panel1

  const int fr = lane & 15;
  const int swzc = ((lane >> 4) ^ ((fr >> 1) & 3)) << 4;
  const int aoff = (wr * 64 + fr) * 64 + swzc;
  const int boff = (wc * 64 + fr) * 64 + swzc;

  f32x4 accP[2][4][4];
#pragma unroll
  for (int p = 0; p < 2; ++p)
#pragma unroll
    for (int mi = 0; mi < 4; ++mi)
#pragma unroll
      for (int ni = 0; ni < 4; ++ni) accP[p][mi][ni] = {0.f, 0.f, 0.f, 0.f};

  auto stage = [&](int kt, int b) {          // 6 gld16, always
    const int k0 = kt * 32;
    char* base = lds + b * 24576;
#pragma unroll
    for (int i = 0; i < 2; ++i)
      gld16(hb + sA[i] + k0, base + ldsO[i]);
#pragma unroll
    for (int i = 0; i < 2; ++i)
      gld16(w2b + sB[i] + k0, base + 8192 + ldsO[i]);
#pragma unroll
    for (int i = 0; i < 2; ++i)
      gld16(w2b + sB[i] + sBp + k0, base + 16384 + ldsO[i]);
  };

  stage(0, 0);
  stage(1, 1);
  asm volatile("s_waitcnt vmcnt(6)" ::: "memory");
  __builtin_amdgcn_sched_barrier(0);
  __builtin_amdgcn_s_barrier();
  __builtin_amdgcn_sched_barrier(0);

  int bR = 0, bS = 2;                        // read buf, stage buf
#pragma unroll 3
  for (int kt = 0; kt < NT; ++kt) {
    const int t2 = (kt + 2 < NT) ? kt + 2 : NT - 1;   // clamp: uniform counts
    stage(t2, bS);
    char* base = lds + bR * 24576;
    s16x8 af[4], b0f[4], b1f[4];
#pragma unroll
    for (int mi = 0; mi < 4; ++mi)
      af[mi] = *(const s16x8*)(base + aoff + mi * 1024);
#pragma unroll
    for (int ni = 0; ni < 4; ++ni) {
      b0f[ni] = *(const s16x8*)(base + 8192 + boff + ni * 1024);
      b1f[ni] = *(const s16x8*)(base + 16384 + boff + ni * 1024);
    }
    __builtin_amdgcn_s_setprio(1);
#pragma unroll
    for (int mi = 0; mi < 4; ++mi)
#pragma unroll
      for (int ni = 0; ni < 4; ++ni) {
        accP[0][mi][ni] = __builtin_amdgcn_mfma_f32_16x16x32_bf16(
            af[mi], b0f[ni], accP[0][mi][ni], 0, 0, 0);
        accP[1][mi][ni] = __builtin_amdgcn_mfma_f32_16x16x32_bf16(
            af[mi], b1f[ni], accP[1][mi][ni], 0, 0, 0);
      }
    __builtin_amdgcn_s_setprio(0);
    asm volatile("s_waitcnt vmcnt(6)" ::: "memory");   // tile kt+1 published
    __builtin_amdgcn_sched_barrier(0);
    __builtin_amdgcn_s_barrier();
    __builtin_amdgcn_sched_barrier(0);
    bR = (bR == 2) ? 0 : bR + 1;
    bS = (bS == 2) ? 0 : bS + 1;
  }

  const int erow = (lane >> 4) * 4;
  const int ecol = lane & 15;
#pragma unroll
  for (int mi = 0; mi < 4; ++mi)
#pragma unroll
    for (int j = 0; j < 4; ++j) {
      const int i = mt * 128 + wr * 64 + mi * 16 + erow + j;
      if (i < count) {
        const uint32_t info = (uint32_t)lst[i];
        const int tok = (int)(info & 0x7fffffffu);
        const float wt = ewts[e * N_TOK + i];
        float* prow = out + (size_t)tok * DIM;
#pragma unroll
        for (int p = 0; p < 2; ++p)
#pragma unroll
          for (int ni = 0; ni < 4; ++ni) {
            const int cb = bn0 + p * 128 + wc * 64 + ni * 16 + ecol;
            atomicAdd(prow + cb, wt * accP[p][mi][ni][j]);
          }
      }
    }
}

extern "C" void kernel_launch(void* const* d_in, const int* in_sizes, int n_in,
                              void* d_out, int out_size, void* d_ws, size_t ws_size,
                              hipStream_t stream) {
  const float* stm = (const float*)d_in[0];
  const float* gw = (const float*)d_in[1];
  const float* w1 = (const float*)d_in[2];
  const float* w2 = (const float*)d_in[3];
  const float* w3 = (const float*)d_in[4];
  float* out = (float*)d_out;
  char* ws = (char*)d_ws;

  __hip_bfloat16* xb = (__hip_bfloat16*)(ws + XB_OFF);
  __hip_bfloat16* hb = (__hip_bfloat16*)(ws + HB_OFF);
  __hip_bfloat16* wb1 = (__hip_bfloat16*)(ws + WB1_OFF);
  __hip_bfloat16* wb3 = (__hip_bfloat16*)(ws + WB3_OFF);
  __hip_bfloat16* w2full = (__hip_bfloat16*)(ws + WB1_OFF);  // 134MB spans wb1+wb3
  int* cnt = (int*)(ws + CNT_OFF);
  int* ebase = (int*)(ws + EBASE_OFF);
  int* elist = (int*)(ws + ELIST_OFF);
  float* ewts = (float*)(ws + EWTS_OFF);

  init_k<<<1, 64, 0, stream>>>(cnt);
  // FAT router: 8192 route + 4096 conv-w1h0->wb1 + 4096 conv-w3h0->wb3 + 512 zero
  router_k<<<N_TOK + 8704, 256, 0, stream>>>(stm, gw, xb, cnt, elist, ewts,
                                             w1, w3, wb1, wb3, out);
  scan_k<<<1, 64, 0, stream>>>(cnt, ebase);

  const dim3 gUp(16, 64, 8);   // (N-panels/half, M-tiles, experts)
  const dim3 gDn(8, 64, 8);    // (256-col D panels fastest, M-tiles, experts)

  // up F-half 0 (weights converted by fat router)
  moe_up_k<<<gUp, 256, 0, stream>>>(xb, wb1, wb3, hb, cnt, ebase, elist, 0);

  // convert w1h1 -> wb1 and w3h1 -> wb3 in ONE launch, then up F-half 1
  convH_k<<<4096, 256, 0, stream>>>(w1, wb1, w3, wb3, 2048);
  moe_up_k<<<gUp, 256, 0, stream>>>(xb, wb1, wb3, hb, cnt, ebase, elist, 2048);

  // full w2 -> bf16 (wb1+wb3 both dead), then one fused down launch
  convW_k<<<4096, 256, 0, stream>>>(w2, w2full, 0, 2048, DIM, FDIM);
  moe_down_k<<<gDn, 256, 0, stream>>>(hb, w2full, out, cnt, ebase, elist, ewts);
}